// Round 1
// baseline (471.431 us; speedup 1.0000x reference)
//
#include <hip/hip_runtime.h>

#define BB 512
#define TT 1000
#define CC 64
#define HH 128
#define TDA_F 150
#define NCLS 4
#define EPSV 1e-5f
#define CHUNK 8
#define NCHUNK (TT / CHUNK)  // 125

// ---------------------------------------------------------------------------
// Kernel 1: fused input-current GEMM + LIF scan.
// Grid: 512 blocks (one per batch b), 128 threads (one per hidden h).
// Each thread keeps W_fc[h][0:64] in VGPRs; kin rows are staged in LDS in
// 8-step double-buffered chunks (coalesced float4 global loads) and read
// back with uniform-address float4 loads (broadcast, conflict-free).
// ---------------------------------------------------------------------------
__global__ __launch_bounds__(HH) void snn_scan(
    const float* __restrict__ kin, const float* __restrict__ Wfc,
    const float* __restrict__ bfc, float* __restrict__ counts_out)
{
  const int b = blockIdx.x;
  const int h = threadIdx.x;

  // W_fc row -> registers (64 VGPRs). One-time, L2-served (W_fc is 32 KB).
  float w[CC];
  const float4* wrow = (const float4*)(Wfc + h * CC);
#pragma unroll
  for (int i = 0; i < CC / 4; ++i) {
    float4 v = wrow[i];
    w[4 * i + 0] = v.x; w[4 * i + 1] = v.y;
    w[4 * i + 2] = v.z; w[4 * i + 3] = v.w;
  }
  const float bias = bfc[h];

  __shared__ float kbuf[2][CHUNK * CC];  // 2 x 2048 B... (2*512 floats = 4 KB)
  const float4* kin_b = (const float4*)(kin + (size_t)b * TT * CC);

  // Stage chunk 0: 128 float4 = 512 floats, one float4 per thread, coalesced.
  {
    float4 r0 = kin_b[h];
    ((float4*)kbuf[0])[h] = r0;
  }

  float mem = 0.0f, cnt = 0.0f;

  for (int tc = 0; tc < NCHUNK; ++tc) {
    float4 r;
    const bool have_next = (tc + 1 < NCHUNK);
    if (have_next) r = kin_b[(tc + 1) * (CHUNK * CC / 4) + h];  // prefetch

    __syncthreads();  // kbuf[tc&1] writes visible; prev reads of other buf done

    const float* buf = kbuf[tc & 1];
#pragma unroll
    for (int s = 0; s < CHUNK; ++s) {
      const float4* kr = (const float4*)(buf + s * CC);
      float a0 = bias, a1 = 0.0f, a2 = 0.0f, a3 = 0.0f;
#pragma unroll
      for (int i = 0; i < CC / 4; ++i) {
        float4 k = kr[i];  // uniform address across lanes -> LDS broadcast
        a0 = fmaf(k.x, w[4 * i + 0], a0);
        a1 = fmaf(k.y, w[4 * i + 1], a1);
        a2 = fmaf(k.z, w[4 * i + 2], a2);
        a3 = fmaf(k.w, w[4 * i + 3], a3);
      }
      const float cur = (a0 + a1) + (a2 + a3);
      mem = fmaf(0.9f, mem, cur);
      const bool spk = (mem >= 1.0f);
      cnt += spk ? 1.0f : 0.0f;
      mem = spk ? 0.0f : mem;
    }

    // Store prefetched chunk into the other buffer (safe: that buffer's last
    // readers finished before the barrier above).
    if (have_next) ((float4*)kbuf[(tc + 1) & 1])[h] = r;
  }

  counts_out[b * HH + h] = cnt;
}

// ---------------------------------------------------------------------------
// Kernel 2: tda_net — 150 -> 64 relu -> 64 relu. One block per sample.
// ---------------------------------------------------------------------------
__global__ __launch_bounds__(64) void tda_net(
    const float* __restrict__ tda, const float* __restrict__ W1,
    const float* __restrict__ b1, const float* __restrict__ W2,
    const float* __restrict__ b2, float* __restrict__ tda_out)
{
  const int b = blockIdx.x, j = threadIdx.x;
  __shared__ float x[TDA_F];
  __shared__ float h1[64];
  for (int i = j; i < TDA_F; i += 64) x[i] = tda[b * TDA_F + i];
  __syncthreads();
  float acc = b1[j];
  const float* wr = W1 + j * TDA_F;
#pragma unroll 5
  for (int i = 0; i < TDA_F; ++i) acc = fmaf(x[i], wr[i], acc);
  h1[j] = fmaxf(acc, 0.0f);
  __syncthreads();
  float acc2 = b2[j];
  const float* w2r = W2 + j * 64;
#pragma unroll
  for (int i = 0; i < 64; ++i) acc2 = fmaf(h1[i], w2r[i], acc2);
  tda_out[b * 64 + j] = fmaxf(acc2, 0.0f);
}

// ---------------------------------------------------------------------------
// Kernel 3: h = fused @ W_c1^T + b_c1 ; accumulate batch column sums/sumsq.
// fused = [counts/T (128), tda_out (64)]. One block per sample, 128 threads.
// ---------------------------------------------------------------------------
__global__ __launch_bounds__(HH) void classifier1(
    const float* __restrict__ counts, const float* __restrict__ tda_out,
    const float* __restrict__ Wc1, const float* __restrict__ bc1,
    float* __restrict__ hbuf, float* __restrict__ colstats /* [2*128] */)
{
  const int b = blockIdx.x, j = threadIdx.x;
  __shared__ float f[HH + 64];
  f[j] = counts[b * HH + j] * (1.0f / TT);
  if (j < 64) f[HH + j] = tda_out[b * 64 + j];
  __syncthreads();
  float acc = bc1[j];
  const float* wr = Wc1 + j * (HH + 64);
#pragma unroll 4
  for (int i = 0; i < HH + 64; ++i) acc = fmaf(f[i], wr[i], acc);
  hbuf[b * HH + j] = acc;
  atomicAdd(&colstats[j], acc);
  atomicAdd(&colstats[HH + j], acc * acc);
}

// ---------------------------------------------------------------------------
// Kernel 4: batchnorm (batch stats, biased var) + relu + final 128->4 GEMM.
// One block per sample, 128 threads; LDS tree-reduce for the 4 outputs.
// ---------------------------------------------------------------------------
__global__ __launch_bounds__(HH) void classifier2(
    const float* __restrict__ hbuf, const float* __restrict__ colstats,
    const float* __restrict__ gamma, const float* __restrict__ beta,
    const float* __restrict__ Wc2, const float* __restrict__ bc2,
    float* __restrict__ out)
{
  const int b = blockIdx.x, j = threadIdx.x;
  const float mean = colstats[j] * (1.0f / BB);
  const float ex2 = colstats[HH + j] * (1.0f / BB);
  const float var = ex2 - mean * mean;
  float hn = (hbuf[b * HH + j] - mean) * rsqrtf(var + EPSV) * gamma[j] + beta[j];
  hn = fmaxf(hn, 0.0f);

  __shared__ float red[NCLS][HH];
#pragma unroll
  for (int k = 0; k < NCLS; ++k) red[k][j] = hn * Wc2[k * HH + j];
  __syncthreads();
  for (int off = HH / 2; off >= 1; off >>= 1) {
    if (j < off) {
#pragma unroll
      for (int k = 0; k < NCLS; ++k) red[k][j] += red[k][j + off];
    }
    __syncthreads();
  }
  if (j < NCLS) out[b * NCLS + j] = red[j][0] + bc2[j];
}

// ---------------------------------------------------------------------------
extern "C" void kernel_launch(void* const* d_in, const int* in_sizes, int n_in,
                              void* d_out, int out_size, void* d_ws, size_t ws_size,
                              hipStream_t stream)
{
  const float* kin  = (const float*)d_in[0];   // [512,1000,64]
  const float* tda  = (const float*)d_in[1];   // [512,150]
  const float* Wfc  = (const float*)d_in[2];   // [128,64]
  const float* bfc  = (const float*)d_in[3];   // [128]
  const float* Wt1  = (const float*)d_in[4];   // [64,150]
  const float* bt1  = (const float*)d_in[5];   // [64]
  const float* Wt2  = (const float*)d_in[6];   // [64,64]
  const float* bt2  = (const float*)d_in[7];   // [64]
  const float* Wc1  = (const float*)d_in[8];   // [128,192]
  const float* bc1  = (const float*)d_in[9];   // [128]
  const float* gam  = (const float*)d_in[10];  // [128]
  const float* bet  = (const float*)d_in[11];  // [128]
  const float* Wc2  = (const float*)d_in[12];  // [4,128]
  const float* bc2  = (const float*)d_in[13];  // [4]

  float* out    = (float*)d_out;        // output 0: [512,4]
  float* counts = out + BB * NCLS;      // output 1: [512,128]

  float* tda_out  = (float*)d_ws;               // [512,64]
  float* hbuf     = tda_out + BB * 64;          // [512,128]
  float* colstats = hbuf + BB * HH;             // [256]

  hipMemsetAsync(colstats, 0, 2 * HH * sizeof(float), stream);

  snn_scan<<<BB, HH, 0, stream>>>(kin, Wfc, bfc, counts);
  tda_net<<<BB, 64, 0, stream>>>(tda, Wt1, bt1, Wt2, bt2, tda_out);
  classifier1<<<BB, HH, 0, stream>>>(counts, tda_out, Wc1, bc1, hbuf, colstats);
  classifier2<<<BB, HH, 0, stream>>>(hbuf, colstats, gam, bet, Wc2, bc2, out);
}